// Round 2
// baseline (927.978 us; speedup 1.0000x reference)
//
#include <hip/hip_runtime.h>
#include <hip/hip_bf16.h>
#include <stdint.h>

#define N_NODES 100000
#define N_EDGES 3200000
#define N_GRAPHS 64
#define NCHUNK 391  // ceil(N_NODES/256)

typedef unsigned int u32;
typedef unsigned short u16;
typedef __attribute__((ext_vector_type(8))) short bf16x8;
typedef __attribute__((ext_vector_type(4))) float f32x4;

__device__ __forceinline__ float bf_lo(u32 u){ return __uint_as_float(u << 16); }
__device__ __forceinline__ float bf_hi(u32 u){ return __uint_as_float(u & 0xffff0000u); }
__device__ __forceinline__ u16 f2bf(float f){
    union { __hip_bfloat16 h; u16 u; } c; c.h = __float2bfloat16(f); return c.u;
}
__device__ __forceinline__ u32 pack2(float a, float b){
    return (u32)f2bf(a) | ((u32)f2bf(b) << 16);
}

// ---- degree histogram (in-degree at dst), 4 edges/thread ----
__global__ void k_deg(const int* __restrict__ dst, int* __restrict__ deg){
    int i = blockIdx.x * blockDim.x + threadIdx.x;  // N_EDGES/4 threads
    int4 d = reinterpret_cast<const int4*>(dst)[i];
    atomicAdd(&deg[d.x], 1); atomicAdd(&deg[d.y], 1);
    atomicAdd(&deg[d.z], 1); atomicAdd(&deg[d.w], 1);
}

// ---- scan pass 1 (block sums) + dinv computation fused ----
__global__ void k_scan1(const int* __restrict__ deg, int* __restrict__ bsum,
                        float* __restrict__ dinv){
    __shared__ int sm[256];
    int idx = blockIdx.x * 256 + threadIdx.x;
    int d = (idx < N_NODES) ? deg[idx] : 0;
    if (idx < N_NODES) dinv[idx] = rsqrtf((float)d + 1.0f);  // +1 self loop
    sm[threadIdx.x] = d;
    __syncthreads();
    for (int off = 128; off > 0; off >>= 1){
        if (threadIdx.x < off) sm[threadIdx.x] += sm[threadIdx.x + off];
        __syncthreads();
    }
    if (threadIdx.x == 0) bsum[blockIdx.x] = sm[0];
}

__global__ void k_scan2(const int* __restrict__ bsum, int* __restrict__ bpre){
    __shared__ int sm[512];
    int tid = threadIdx.x;
    int v = (tid < NCHUNK) ? bsum[tid] : 0;
    sm[tid] = v; __syncthreads();
    for (int off = 1; off < 512; off <<= 1){
        int t = (tid >= off) ? sm[tid - off] : 0;
        __syncthreads(); sm[tid] += t; __syncthreads();
    }
    if (tid < NCHUNK) bpre[tid] = sm[tid] - v;  // exclusive
}

__global__ void k_scan3(const int* __restrict__ deg, const int* __restrict__ bpre,
                        int* __restrict__ offsets, int* __restrict__ cursor){
    __shared__ int sm[256];
    int idx = blockIdx.x * 256 + threadIdx.x;
    int v = (idx < N_NODES) ? deg[idx] : 0;
    sm[threadIdx.x] = v; __syncthreads();
    for (int off = 1; off < 256; off <<= 1){
        int t = (threadIdx.x >= off) ? sm[threadIdx.x - off] : 0;
        __syncthreads(); sm[threadIdx.x] += t; __syncthreads();
    }
    int excl = sm[threadIdx.x] - v + bpre[blockIdx.x];
    if (idx < N_NODES){ offsets[idx] = excl; cursor[idx] = excl; }
    if (blockIdx.x == 0 && threadIdx.x == 0) offsets[N_NODES] = N_EDGES;
}

// ---- fill CSR buckets: ONE 4B store per edge (norm factorized away) ----
__global__ void k_fill(const int* __restrict__ src, const int* __restrict__ dst,
                       int* __restrict__ cursor, int* __restrict__ csr_src){
    int i = blockIdx.x * blockDim.x + threadIdx.x;  // N_EDGES/4 threads
    int4 s = reinterpret_cast<const int4*>(src)[i];
    int4 d = reinterpret_cast<const int4*>(dst)[i];
    csr_src[atomicAdd(&cursor[d.x], 1)] = s.x;
    csr_src[atomicAdd(&cursor[d.y], 1)] = s.y;
    csr_src[atomicAdd(&cursor[d.z], 1)] = s.z;
    csr_src[atomicAdd(&cursor[d.w], 1)] = s.w;
}

// ---- f32 -> bf16 with dinv[row] folded in; 4 floats/thread ----
__global__ void k_cvt_x(const float* __restrict__ x, const float* __restrict__ dinv,
                        u32* __restrict__ xb){
    int i = blockIdx.x * blockDim.x + threadIdx.x;  // N_NODES*32
    if (i < N_NODES * 32){
        float w = dinv[i >> 5];
        float4 f = reinterpret_cast<const float4*>(x)[i];
        uint2 p = make_uint2(pack2(f.x * w, f.y * w), pack2(f.z * w, f.w * w));
        reinterpret_cast<uint2*>(xb)[i] = p;
    }
}

// ---- both weight transposes in one launch: W[K][N] f32 -> WT[N][K] bf16 ----
__global__ void k_cvt_w(const float* __restrict__ W1, const float* __restrict__ W2,
                        u16* __restrict__ w1t, u16* __restrict__ w2t){
    int i = blockIdx.x * blockDim.x + threadIdx.x;
    if (i < 128 * 256){           // W1: K=128, N=256
        int n = i / 128, k = i % 128;
        w1t[i] = f2bf(W1[k * 256 + n]);
    } else {                      // W2: K=256, N=128
        int j = i - 128 * 256;
        int n = j / 256, k = j % 256;
        w2t[j] = f2bf(W2[k * 128 + n]);
    }
}

// ---- edge aggregation: out[v] = dinv[v] * (X'[v] + sum_{s in N(v)} X'[s])
// X' is bf16 [N][128] (pre-scaled by dinv[src]) as packed u32 pairs.
// One 64-lane group per node, 2 channels/lane. Pure gather-add, no atomics.
template<bool OUT_BF16>
__global__ __launch_bounds__(256) void k_agg(const u32* __restrict__ X,
                      const int* __restrict__ offs, const int* __restrict__ csr_src,
                      const float* __restrict__ dinv, void* __restrict__ out){
    int lane = threadIdx.x & 63;
    int v = blockIdx.x * 4 + (threadIdx.x >> 6);
    u32 u = X[v * 64 + lane];
    float a0 = bf_lo(u), a1 = bf_hi(u);
    int e1 = offs[v + 1];
    for (int e = offs[v]; e < e1; e += 64){
        int idx = e + lane;
        int sv = (idx < e1) ? csr_src[idx] : 0;
        int cnt = min(64, e1 - e);
        int j = 0;
        for (; j + 4 <= cnt; j += 4){
            int s0 = __shfl(sv, j), s1 = __shfl(sv, j+1), s2 = __shfl(sv, j+2), s3 = __shfl(sv, j+3);
            u32 u0 = X[s0*64 + lane], u1 = X[s1*64 + lane], u2 = X[s2*64 + lane], u3 = X[s3*64 + lane];
            a0 += (bf_lo(u0) + bf_lo(u1)) + (bf_lo(u2) + bf_lo(u3));
            a1 += (bf_hi(u0) + bf_hi(u1)) + (bf_hi(u2) + bf_hi(u3));
        }
        for (; j < cnt; j++){
            int s = __shfl(sv, j);
            u32 uu = X[s*64 + lane];
            a0 += bf_lo(uu); a1 += bf_hi(uu);
        }
    }
    float w = dinv[v];
    a0 *= w; a1 *= w;
    if (OUT_BF16){
        ((u32*)out)[v*64 + lane] = pack2(a0, a1);
    } else {
        ((float2*)out)[v*64 + lane] = make_float2(a0, a1);
    }
}

// ---- bf16 MFMA GEMM: C[M][BN] = A[M][BK] @ BT[BN][BK]^T (+bias)(+relu)(*rowscale)
// block: 256 thr (4 waves), BM=64 rows/block, each wave 16 rows x BN cols.
// LDS XOR-swizzle (byte ^= (row&7)<<4) kills the stride-256/512B bank conflict.
template<int BK, int BN, bool RELU, bool BIAS, bool SCALE>
__global__ __launch_bounds__(256) void k_gemm(const u16* __restrict__ A, const u16* __restrict__ BT,
                        const float* __restrict__ bias, const float* __restrict__ rowscale,
                        u16* __restrict__ C, int M){
    extern __shared__ char smem[];
    char* As = smem;                      // 64 x BK bf16, swizzled
    char* Bs = smem + 64 * BK * 2;        // BN x BK bf16, swizzled
    const int tid = threadIdx.x;
    const int rowbytes = BK * 2;
    {
        const int a16 = 64 * rowbytes / 16;
        for (int it = tid; it < a16; it += 256){
            int flat = it * 16;
            int r = flat / rowbytes, cb = flat % rowbytes;
            int grow = blockIdx.x * 64 + r;
            int4 val = make_int4(0,0,0,0);
            if (grow < M) val = *reinterpret_cast<const int4*>(A + grow * BK + cb / 2);
            *reinterpret_cast<int4*>(As + r * rowbytes + (cb ^ ((r & 7) << 4))) = val;
        }
        const int b16 = BN * rowbytes / 16;
        for (int it = tid; it < b16; it += 256){
            int flat = it * 16;
            int r = flat / rowbytes, cb = flat % rowbytes;
            int4 val = *reinterpret_cast<const int4*>(BT + r * BK + cb / 2);
            *reinterpret_cast<int4*>(Bs + r * rowbytes + (cb ^ ((r & 7) << 4))) = val;
        }
    }
    __syncthreads();

    const int wid = tid >> 6, lane = tid & 63;
    const int r0 = wid * 16;
    constexpr int NF = BN / 16;
    f32x4 acc[NF];
#pragma unroll
    for (int i = 0; i < NF; i++) acc[i] = (f32x4){0.f,0.f,0.f,0.f};
    const int ar = r0 + (lane & 15);
    const int koff = (lane >> 4) * 8;   // element offset within k-slice
#pragma unroll
    for (int kb = 0; kb < BK / 32; kb++){
        int kbyte = (kb * 32 + koff) * 2;
        bf16x8 aF = *reinterpret_cast<const bf16x8*>(As + ar * rowbytes + (kbyte ^ ((ar & 7) << 4)));
#pragma unroll
        for (int nf = 0; nf < NF; nf++){
            int bn = nf * 16 + (lane & 15);
            bf16x8 bF = *reinterpret_cast<const bf16x8*>(Bs + bn * rowbytes + (kbyte ^ ((bn & 7) << 4)));
            acc[nf] = __builtin_amdgcn_mfma_f32_16x16x32_bf16(aF, bF, acc[nf], 0, 0, 0);
        }
    }
#pragma unroll
    for (int nf = 0; nf < NF; nf++){
        int col = nf * 16 + (lane & 15);
        float bv = BIAS ? bias[col] : 0.f;
#pragma unroll
        for (int j = 0; j < 4; j++){
            int grow = blockIdx.x * 64 + r0 + (lane >> 4) * 4 + j;
            if (grow < M){
                float val = acc[nf][j] + bv;
                if (RELU) val = fmaxf(val, 0.f);
                if (SCALE) val *= rowscale[grow];
                C[grow * BN + col] = f2bf(val);
            }
        }
    }
}

// ---- pool: batch is sorted; run-accumulate in regs, flush per graph-run ----
__global__ void k_pool(const float* __restrict__ agg2f, const int* __restrict__ batch,
                       float* __restrict__ psum, float* __restrict__ counts){
    const int NPB = 200;  // grid=500
    int n0 = blockIdx.x * NPB, n1 = min(n0 + NPB, N_NODES);
    int tid = threadIdx.x;  // 128 = channel
    float racc = 0.f; int gcur = batch[n0]; int runlen = 0;
    for (int n = n0; n < n1; n++){
        int g = batch[n];
        if (g != gcur){
            atomicAdd(&psum[gcur * 128 + tid], racc);
            if (tid == 0) atomicAdd(&counts[gcur], (float)runlen);
            racc = 0.f; runlen = 0; gcur = g;
        }
        racc += agg2f[n * 128 + tid];
        runlen++;
    }
    atomicAdd(&psum[gcur * 128 + tid], racc);
    if (tid == 0) atomicAdd(&counts[gcur], (float)runlen);
}

__global__ void k_final(const float* __restrict__ psum, const float* __restrict__ counts,
                        const float* __restrict__ b2, float* __restrict__ out){
    int g = blockIdx.x, c = threadIdx.x;
    out[g * 128 + c] = psum[g * 128 + c] / fmaxf(counts[g], 1.0f) + b2[c];
}

extern "C" void kernel_launch(void* const* d_in, const int* in_sizes, int n_in,
                              void* d_out, int out_size, void* d_ws, size_t ws_size,
                              hipStream_t stream){
    const float* x   = (const float*)d_in[0];
    const int*   ei  = (const int*)d_in[1];
    const int* batch = (const int*)d_in[2];
    const float* W1  = (const float*)d_in[3];
    const float* b1  = (const float*)d_in[4];
    const float* W2  = (const float*)d_in[5];
    const float* b2  = (const float*)d_in[6];
    float* out = (float*)d_out;
    const int* esrc = ei;
    const int* edst = ei + N_EDGES;

    char* w = (char*)d_ws;
    size_t off = 0;
    auto alloc = [&](size_t bytes) -> char* {
        char* p = w + off; off += (bytes + 255) & ~size_t(255); return p;
    };
    int*   deg      = (int*)  alloc((size_t)N_NODES * 4);
    float* dinv     = (float*)alloc((size_t)N_NODES * 4);
    int*   offsets  = (int*)  alloc((size_t)(N_NODES + 1) * 4);
    int*   cursor   = (int*)  alloc((size_t)N_NODES * 4);
    int*   bsum     = (int*)  alloc((size_t)NCHUNK * 4);
    int*   bpre     = (int*)  alloc((size_t)NCHUNK * 4);
    int*   csr_src  = (int*)  alloc((size_t)N_EDGES * 4);
    u32*   xb       = (u32*)  alloc((size_t)N_NODES * 64 * 4);   // bf16 [N][128] prescaled
    u16*   aggx     = (u16*)  alloc((size_t)N_NODES * 128 * 2);  // bf16 [N][128]
    u16*   h        = (u16*)  alloc((size_t)N_NODES * 256 * 2);  // bf16 [N][256]
    u16*   t        = (u16*)  alloc((size_t)N_NODES * 128 * 2);  // bf16 [N][128] prescaled
    u16*   w1t      = (u16*)  alloc(128 * 256 * 2);
    u16*   w2t      = (u16*)  alloc(256 * 128 * 2);
    float* psum     = (float*)alloc((size_t)N_GRAPHS * 128 * 4);
    float* counts   = (float*)alloc((size_t)N_GRAPHS * 4);
    float* agg2f    = (float*)h;  // alias: h dead once t computed; agg2 f32 [N][128]

    hipMemsetAsync(deg, 0, (size_t)N_NODES * 4, stream);
    hipMemsetAsync(psum, 0, (size_t)N_GRAPHS * 128 * 4, stream);
    hipMemsetAsync(counts, 0, (size_t)N_GRAPHS * 4, stream);

    k_deg  <<<3125, 256, 0, stream>>>(edst, deg);
    k_scan1<<<NCHUNK, 256, 0, stream>>>(deg, bsum, dinv);
    k_scan2<<<1, 512, 0, stream>>>(bsum, bpre);
    k_scan3<<<NCHUNK, 256, 0, stream>>>(deg, bpre, offsets, cursor);
    k_fill <<<3125, 256, 0, stream>>>(esrc, edst, cursor, csr_src);
    k_cvt_x<<<12500, 256, 0, stream>>>(x, dinv, xb);
    k_cvt_w<<<256, 256, 0, stream>>>(W1, W2, w1t, w2t);

    // layer 1: aggx = dinv*(sum of prescaled x rows)  (bf16), h = relu(aggx@W1+b1)
    k_agg<true><<<25000, 256, 0, stream>>>(xb, offsets, csr_src, dinv, aggx);

    hipFuncSetAttribute(reinterpret_cast<const void*>(&k_gemm<128, 256, true, true, false>),
                        hipFuncAttributeMaxDynamicSharedMemorySize, 64*128*2 + 256*128*2);
    hipFuncSetAttribute(reinterpret_cast<const void*>(&k_gemm<256, 128, false, false, true>),
                        hipFuncAttributeMaxDynamicSharedMemorySize, 64*256*2 + 128*256*2);

    k_gemm<128, 256, true, true, false><<<1563, 256, 64*128*2 + 256*128*2, stream>>>(
        aggx, w1t, b1, nullptr, h, N_NODES);
    // layer 2: t = (h@W2)*dinv[row] (bf16, prescaled), agg2f = dinv*(sum of t rows) (f32)
    k_gemm<256, 128, false, false, true><<<1563, 256, 64*256*2 + 128*256*2, stream>>>(
        h, w2t, nullptr, dinv, t, N_NODES);
    k_agg<false><<<25000, 256, 0, stream>>>((const u32*)t, offsets, csr_src, dinv, (void*)agg2f);
    k_pool <<<500, 128, 0, stream>>>(agg2f, batch, psum, counts);
    k_final<<<N_GRAPHS, 128, 0, stream>>>(psum, counts, b2, out);
}

// Round 3
// 755.408 us; speedup vs baseline: 1.2284x; 1.2284x over previous
//
#include <hip/hip_runtime.h>
#include <hip/hip_bf16.h>
#include <stdint.h>

#define N_NODES 100000
#define N_EDGES 3200000
#define N_GRAPHS 64
#define NCHUNK 391   // ceil(N_NODES/256) for node scans
#define BSH 8        // bucket = 256 nodes
#define NB 391       // ceil(100000/256) buckets
#define G_SC 512     // scatter blocks
#define EPB 6250     // edges per scatter block (512*6250 == 3200000 exactly)

typedef unsigned int u32;
typedef unsigned short u16;
typedef __attribute__((ext_vector_type(8))) short bf16x8;
typedef __attribute__((ext_vector_type(4))) float f32x4;

__device__ __forceinline__ float bf_lo(u32 u){ return __uint_as_float(u << 16); }
__device__ __forceinline__ float bf_hi(u32 u){ return __uint_as_float(u & 0xffff0000u); }
__device__ __forceinline__ u16 f2bf(float f){
    union { __hip_bfloat16 h; u16 u; } c; c.h = __float2bfloat16(f); return c.u;
}
__device__ __forceinline__ u32 pack2(float a, float b){
    return (u32)f2bf(a) | ((u32)f2bf(b) << 16);
}

// ---- degree histogram (in-degree at dst), 1 edge/thread for max MLP ----
__global__ void k_deg(const int* __restrict__ dst, int* __restrict__ deg){
    int e = blockIdx.x * blockDim.x + threadIdx.x;
    if (e < N_EDGES) atomicAdd(&deg[dst[e]], 1);
}

// ---- scan pass 1 (block sums) + dinv fused ----
__global__ void k_scan1(const int* __restrict__ deg, int* __restrict__ bsum,
                        float* __restrict__ dinv){
    __shared__ int sm[256];
    int idx = blockIdx.x * 256 + threadIdx.x;
    int d = (idx < N_NODES) ? deg[idx] : 0;
    if (idx < N_NODES) dinv[idx] = rsqrtf((float)d + 1.0f);  // +1 self loop
    sm[threadIdx.x] = d;
    __syncthreads();
    for (int off = 128; off > 0; off >>= 1){
        if (threadIdx.x < off) sm[threadIdx.x] += sm[threadIdx.x + off];
        __syncthreads();
    }
    if (threadIdx.x == 0) bsum[blockIdx.x] = sm[0];
}

__global__ void k_scan2(const int* __restrict__ bsum, int* __restrict__ bpre){
    __shared__ int sm[512];
    int tid = threadIdx.x;
    int v = (tid < NCHUNK) ? bsum[tid] : 0;
    sm[tid] = v; __syncthreads();
    for (int off = 1; off < 512; off <<= 1){
        int t = (tid >= off) ? sm[tid - off] : 0;
        __syncthreads(); sm[tid] += t; __syncthreads();
    }
    if (tid < NCHUNK) bpre[tid] = sm[tid] - v;  // exclusive
}

__global__ void k_scan3(const int* __restrict__ deg, const int* __restrict__ bpre,
                        int* __restrict__ offsets){
    __shared__ int sm[256];
    int idx = blockIdx.x * 256 + threadIdx.x;
    int v = (idx < N_NODES) ? deg[idx] : 0;
    sm[threadIdx.x] = v; __syncthreads();
    for (int off = 1; off < 256; off <<= 1){
        int t = (threadIdx.x >= off) ? sm[threadIdx.x - off] : 0;
        __syncthreads(); sm[threadIdx.x] += t; __syncthreads();
    }
    int excl = sm[threadIdx.x] - v + bpre[blockIdx.x];
    if (idx < N_NODES) offsets[idx] = excl;
    if (blockIdx.x == 0 && threadIdx.x == 0) offsets[N_NODES] = N_EDGES;
}

// ---- A1: per-block coarse histogram over NB buckets (dst>>BSH) ----
__global__ __launch_bounds__(512) void k_hist(const int* __restrict__ dst,
                                              int* __restrict__ hist){
    __shared__ int h[NB];
    int tid = threadIdx.x, g = blockIdx.x;
    for (int i = tid; i < NB; i += 512) h[i] = 0;
    __syncthreads();
    int e0 = g * EPB;
    for (int i = tid; i < EPB; i += 512) atomicAdd(&h[dst[e0 + i] >> BSH], 1);
    __syncthreads();
    for (int i = tid; i < NB; i += 512) hist[i * G_SC + g] = h[i];  // bucket-major
}

// ---- A2: per-bucket exclusive scan over blocks -> (bucket,block) cursors ----
// bucket base comes free from node-level offsets: base[b] = offsets[b<<BSH]
__global__ __launch_bounds__(512) void k_colscan(const int* __restrict__ hist,
                                                 const int* __restrict__ offsets,
                                                 int* __restrict__ cursors){
    __shared__ int sm[512];
    int b = blockIdx.x, tid = threadIdx.x;
    int v = hist[b * G_SC + tid];
    sm[tid] = v; __syncthreads();
    for (int off = 1; off < 512; off <<= 1){
        int t = (tid >= off) ? sm[tid - off] : 0;
        __syncthreads(); sm[tid] += t; __syncthreads();
    }
    cursors[b * G_SC + tid] = sm[tid] - v + offsets[b << BSH];
}

// ---- A3: scatter (src,dst) pairs into coarse buckets; block-private regions ----
__global__ __launch_bounds__(512) void k_scatter(const int* __restrict__ src,
                                                 const int* __restrict__ dst,
                                                 const int* __restrict__ cursors,
                                                 uint2* __restrict__ pairs){
    __shared__ int cur[NB];
    int g = blockIdx.x, tid = threadIdx.x;
    for (int i = tid; i < NB; i += 512) cur[i] = cursors[i * G_SC + g];
    __syncthreads();
    int e0 = g * EPB;
    for (int i = tid; i < EPB; i += 512){
        int s = src[e0 + i], d = dst[e0 + i];
        int pos = atomicAdd(&cur[d >> BSH], 1);
        pairs[pos] = make_uint2((u32)s, (u32)d);
    }
}

// ---- B: fine fill within each bucket; LDS cursors, fully local writes ----
__global__ __launch_bounds__(512) void k_fine(const uint2* __restrict__ pairs,
                                              const int* __restrict__ offsets,
                                              int* __restrict__ csr_src){
    __shared__ int cur[256];
    int b = blockIdx.x, tid = threadIdx.x;
    int node0 = b << BSH;
    if (tid < 256){
        int n = node0 + tid;
        cur[tid] = (n < N_NODES) ? offsets[n] : N_EDGES;
    }
    __syncthreads();
    int e0 = offsets[node0];
    int nend = min(node0 + 256, N_NODES);
    int e1 = offsets[nend];
    for (int e = e0 + tid; e < e1; e += 512){
        uint2 p = pairs[e];
        int pos = atomicAdd(&cur[p.y - node0], 1);
        csr_src[pos] = (int)p.x;
    }
}

// ---- f32 -> bf16 with dinv[row] folded in; 4 floats/thread ----
__global__ void k_cvt_x(const float* __restrict__ x, const float* __restrict__ dinv,
                        u32* __restrict__ xb){
    int i = blockIdx.x * blockDim.x + threadIdx.x;  // N_NODES*32
    if (i < N_NODES * 32){
        float w = dinv[i >> 5];
        float4 f = reinterpret_cast<const float4*>(x)[i];
        uint2 p = make_uint2(pack2(f.x * w, f.y * w), pack2(f.z * w, f.w * w));
        reinterpret_cast<uint2*>(xb)[i] = p;
    }
}

// ---- both weight transposes in one launch: W[K][N] f32 -> WT[N][K] bf16 ----
__global__ void k_cvt_w(const float* __restrict__ W1, const float* __restrict__ W2,
                        u16* __restrict__ w1t, u16* __restrict__ w2t){
    int i = blockIdx.x * blockDim.x + threadIdx.x;
    if (i < 128 * 256){           // W1: K=128, N=256
        int n = i / 128, k = i % 128;
        w1t[i] = f2bf(W1[k * 256 + n]);
    } else {                      // W2: K=256, N=128
        int j = i - 128 * 256;
        int n = j / 256, k = j % 256;
        w2t[j] = f2bf(W2[k * 128 + n]);
    }
}

// ---- edge aggregation: out[v] = dinv[v] * (X'[v] + sum_{s in N(v)} X'[s])
// X' is bf16 [N][128] (pre-scaled by dinv[src]) as packed u32 pairs.
// One 64-lane group per node, 2 channels/lane. Pure gather-add, no atomics.
template<bool OUT_BF16>
__global__ __launch_bounds__(256) void k_agg(const u32* __restrict__ X,
                      const int* __restrict__ offs, const int* __restrict__ csr_src,
                      const float* __restrict__ dinv, void* __restrict__ out){
    int lane = threadIdx.x & 63;
    int v = blockIdx.x * 4 + (threadIdx.x >> 6);
    u32 u = X[v * 64 + lane];
    float a0 = bf_lo(u), a1 = bf_hi(u);
    int e1 = offs[v + 1];
    for (int e = offs[v]; e < e1; e += 64){
        int idx = e + lane;
        int sv = (idx < e1) ? csr_src[idx] : 0;
        int cnt = min(64, e1 - e);
        int j = 0;
        for (; j + 4 <= cnt; j += 4){
            int s0 = __shfl(sv, j), s1 = __shfl(sv, j+1), s2 = __shfl(sv, j+2), s3 = __shfl(sv, j+3);
            u32 u0 = X[s0*64 + lane], u1 = X[s1*64 + lane], u2 = X[s2*64 + lane], u3 = X[s3*64 + lane];
            a0 += (bf_lo(u0) + bf_lo(u1)) + (bf_lo(u2) + bf_lo(u3));
            a1 += (bf_hi(u0) + bf_hi(u1)) + (bf_hi(u2) + bf_hi(u3));
        }
        for (; j < cnt; j++){
            int s = __shfl(sv, j);
            u32 uu = X[s*64 + lane];
            a0 += bf_lo(uu); a1 += bf_hi(uu);
        }
    }
    float w = dinv[v];
    a0 *= w; a1 *= w;
    if (OUT_BF16){
        ((u32*)out)[v*64 + lane] = pack2(a0, a1);
    } else {
        ((float2*)out)[v*64 + lane] = make_float2(a0, a1);
    }
}

// ---- bf16 MFMA GEMM: C[M][BN] = A[M][BK] @ BT[BN][BK]^T (+bias)(+relu)(*rowscale)
template<int BK, int BN, bool RELU, bool BIAS, bool SCALE>
__global__ __launch_bounds__(256) void k_gemm(const u16* __restrict__ A, const u16* __restrict__ BT,
                        const float* __restrict__ bias, const float* __restrict__ rowscale,
                        u16* __restrict__ C, int M){
    extern __shared__ char smem[];
    char* As = smem;                      // 64 x BK bf16, swizzled
    char* Bs = smem + 64 * BK * 2;        // BN x BK bf16, swizzled
    const int tid = threadIdx.x;
    const int rowbytes = BK * 2;
    {
        const int a16 = 64 * rowbytes / 16;
        for (int it = tid; it < a16; it += 256){
            int flat = it * 16;
            int r = flat / rowbytes, cb = flat % rowbytes;
            int grow = blockIdx.x * 64 + r;
            int4 val = make_int4(0,0,0,0);
            if (grow < M) val = *reinterpret_cast<const int4*>(A + grow * BK + cb / 2);
            *reinterpret_cast<int4*>(As + r * rowbytes + (cb ^ ((r & 7) << 4))) = val;
        }
        const int b16 = BN * rowbytes / 16;
        for (int it = tid; it < b16; it += 256){
            int flat = it * 16;
            int r = flat / rowbytes, cb = flat % rowbytes;
            int4 val = *reinterpret_cast<const int4*>(BT + r * BK + cb / 2);
            *reinterpret_cast<int4*>(Bs + r * rowbytes + (cb ^ ((r & 7) << 4))) = val;
        }
    }
    __syncthreads();

    const int wid = tid >> 6, lane = tid & 63;
    const int r0 = wid * 16;
    constexpr int NF = BN / 16;
    f32x4 acc[NF];
#pragma unroll
    for (int i = 0; i < NF; i++) acc[i] = (f32x4){0.f,0.f,0.f,0.f};
    const int ar = r0 + (lane & 15);
    const int koff = (lane >> 4) * 8;   // element offset within k-slice
#pragma unroll
    for (int kb = 0; kb < BK / 32; kb++){
        int kbyte = (kb * 32 + koff) * 2;
        bf16x8 aF = *reinterpret_cast<const bf16x8*>(As + ar * rowbytes + (kbyte ^ ((ar & 7) << 4)));
#pragma unroll
        for (int nf = 0; nf < NF; nf++){
            int bn = nf * 16 + (lane & 15);
            bf16x8 bF = *reinterpret_cast<const bf16x8*>(Bs + bn * rowbytes + (kbyte ^ ((bn & 7) << 4)));
            acc[nf] = __builtin_amdgcn_mfma_f32_16x16x32_bf16(aF, bF, acc[nf], 0, 0, 0);
        }
    }
#pragma unroll
    for (int nf = 0; nf < NF; nf++){
        int col = nf * 16 + (lane & 15);
        float bv = BIAS ? bias[col] : 0.f;
#pragma unroll
        for (int j = 0; j < 4; j++){
            int grow = blockIdx.x * 64 + r0 + (lane >> 4) * 4 + j;
            if (grow < M){
                float val = acc[nf][j] + bv;
                if (RELU) val = fmaxf(val, 0.f);
                if (SCALE) val *= rowscale[grow];
                C[grow * BN + col] = f2bf(val);
            }
        }
    }
}

// ---- pool: batch is sorted; run-accumulate in regs, flush per graph-run ----
__global__ void k_pool(const float* __restrict__ agg2f, const int* __restrict__ batch,
                       float* __restrict__ psum, float* __restrict__ counts){
    const int NPB = 200;  // grid=500
    int n0 = blockIdx.x * NPB, n1 = min(n0 + NPB, N_NODES);
    int tid = threadIdx.x;  // 128 = channel
    float racc = 0.f; int gcur = batch[n0]; int runlen = 0;
    for (int n = n0; n < n1; n++){
        int g = batch[n];
        if (g != gcur){
            atomicAdd(&psum[gcur * 128 + tid], racc);
            if (tid == 0) atomicAdd(&counts[gcur], (float)runlen);
            racc = 0.f; runlen = 0; gcur = g;
        }
        racc += agg2f[n * 128 + tid];
        runlen++;
    }
    atomicAdd(&psum[gcur * 128 + tid], racc);
    if (tid == 0) atomicAdd(&counts[gcur], (float)runlen);
}

__global__ void k_final(const float* __restrict__ psum, const float* __restrict__ counts,
                        const float* __restrict__ b2, float* __restrict__ out){
    int g = blockIdx.x, c = threadIdx.x;
    out[g * 128 + c] = psum[g * 128 + c] / fmaxf(counts[g], 1.0f) + b2[c];
}

extern "C" void kernel_launch(void* const* d_in, const int* in_sizes, int n_in,
                              void* d_out, int out_size, void* d_ws, size_t ws_size,
                              hipStream_t stream){
    const float* x   = (const float*)d_in[0];
    const int*   ei  = (const int*)d_in[1];
    const int* batch = (const int*)d_in[2];
    const float* W1  = (const float*)d_in[3];
    const float* b1  = (const float*)d_in[4];
    const float* W2  = (const float*)d_in[5];
    const float* b2  = (const float*)d_in[6];
    float* out = (float*)d_out;
    const int* esrc = ei;
    const int* edst = ei + N_EDGES;

    char* w = (char*)d_ws;
    size_t off = 0;
    auto alloc = [&](size_t bytes) -> char* {
        char* p = w + off; off += (bytes + 255) & ~size_t(255); return p;
    };
    int*   deg      = (int*)  alloc((size_t)N_NODES * 4);
    float* dinv     = (float*)alloc((size_t)N_NODES * 4);
    int*   offsets  = (int*)  alloc((size_t)(N_NODES + 1) * 4);
    int*   bsum     = (int*)  alloc((size_t)NCHUNK * 4);
    int*   bpre     = (int*)  alloc((size_t)NCHUNK * 4);
    int*   hist     = (int*)  alloc((size_t)NB * G_SC * 4);
    int*   cursors  = (int*)  alloc((size_t)NB * G_SC * 4);
    int*   csr_src  = (int*)  alloc((size_t)N_EDGES * 4);
    u32*   xb       = (u32*)  alloc((size_t)N_NODES * 64 * 4);   // bf16 [N][128] prescaled
    u16*   aggx     = (u16*)  alloc((size_t)N_NODES * 128 * 2);  // bf16 [N][128]
    u16*   h        = (u16*)  alloc((size_t)N_NODES * 256 * 2);  // bf16 [N][256]
    u16*   t        = (u16*)  alloc((size_t)N_NODES * 128 * 2);  // bf16 [N][128] prescaled
    u16*   w1t      = (u16*)  alloc(128 * 256 * 2);
    u16*   w2t      = (u16*)  alloc(256 * 128 * 2);
    float* psum     = (float*)alloc((size_t)N_GRAPHS * 128 * 4);
    float* counts   = (float*)alloc((size_t)N_GRAPHS * 4);
    float* agg2f    = (float*)h;   // alias: h dead once t computed; agg2 f32 [N][128]
    uint2* pairs    = (uint2*)h;   // alias: h not yet written during CSR build (25.6MB < 51.2MB)

    hipMemsetAsync(deg, 0, (size_t)N_NODES * 4, stream);
    hipMemsetAsync(psum, 0, (size_t)N_GRAPHS * 128 * 4, stream);
    hipMemsetAsync(counts, 0, (size_t)N_GRAPHS * 4, stream);

    // degrees + node-level offsets (+dinv)
    k_deg  <<<12500, 256, 0, stream>>>(edst, deg);
    k_scan1<<<NCHUNK, 256, 0, stream>>>(deg, bsum, dinv);
    k_scan2<<<1, 512, 0, stream>>>(bsum, bpre);
    k_scan3<<<NCHUNK, 256, 0, stream>>>(deg, bpre, offsets);

    // counting-sort CSR build: coarse bucket then fine fill (no global scatter atomics)
    k_hist   <<<G_SC, 512, 0, stream>>>(edst, hist);
    k_colscan<<<NB, 512, 0, stream>>>(hist, offsets, cursors);
    k_scatter<<<G_SC, 512, 0, stream>>>(esrc, edst, cursors, pairs);
    k_fine   <<<NB, 512, 0, stream>>>(pairs, offsets, csr_src);

    k_cvt_x<<<12500, 256, 0, stream>>>(x, dinv, xb);
    k_cvt_w<<<256, 256, 0, stream>>>(W1, W2, w1t, w2t);

    // layer 1: aggx = dinv*(sum of prescaled x rows)  (bf16), h = relu(aggx@W1+b1)
    k_agg<true><<<25000, 256, 0, stream>>>(xb, offsets, csr_src, dinv, aggx);

    hipFuncSetAttribute(reinterpret_cast<const void*>(&k_gemm<128, 256, true, true, false>),
                        hipFuncAttributeMaxDynamicSharedMemorySize, 64*128*2 + 256*128*2);
    hipFuncSetAttribute(reinterpret_cast<const void*>(&k_gemm<256, 128, false, false, true>),
                        hipFuncAttributeMaxDynamicSharedMemorySize, 64*256*2 + 128*256*2);

    k_gemm<128, 256, true, true, false><<<1563, 256, 64*128*2 + 256*128*2, stream>>>(
        aggx, w1t, b1, nullptr, h, N_NODES);
    // layer 2: t = (h@W2)*dinv[row] (bf16, prescaled), agg2f = dinv*(sum of t rows) (f32)
    k_gemm<256, 128, false, false, true><<<1563, 256, 64*256*2 + 128*256*2, stream>>>(
        h, w2t, nullptr, dinv, t, N_NODES);
    k_agg<false><<<25000, 256, 0, stream>>>((const u32*)t, offsets, csr_src, dinv, (void*)agg2f);
    k_pool <<<500, 128, 0, stream>>>(agg2f, batch, psum, counts);
    k_final<<<N_GRAPHS, 128, 0, stream>>>(psum, counts, b2, out);
}

// Round 4
// 619.086 us; speedup vs baseline: 1.4989x; 1.2202x over previous
//
#include <hip/hip_runtime.h>
#include <hip/hip_bf16.h>
#include <stdint.h>

#define N_NODES 100000
#define N_EDGES 3200000
#define N_GRAPHS 64
#define BSH 8        // bucket = 256 nodes
#define NB 391       // ceil(100000/256) buckets
#define G_SC 512     // scatter/hist blocks
#define EPB 6250     // edges per scatter block (512*6250 == 3200000 exactly)

typedef unsigned int u32;
typedef unsigned short u16;
typedef __attribute__((ext_vector_type(8))) short bf16x8;
typedef __attribute__((ext_vector_type(4))) float f32x4;

__device__ __forceinline__ float bf_lo(u32 u){ return __uint_as_float(u << 16); }
__device__ __forceinline__ float bf_hi(u32 u){ return __uint_as_float(u & 0xffff0000u); }
__device__ __forceinline__ u16 f2bf(float f){
    union { __hip_bfloat16 h; u16 u; } c; c.h = __float2bfloat16(f); return c.u;
}
__device__ __forceinline__ u32 pack2(float a, float b){
    return (u32)f2bf(a) | ((u32)f2bf(b) << 16);
}

// ---- A1: per-block coarse histogram over NB buckets (dst>>BSH); LDS atomics only ----
__global__ __launch_bounds__(512) void k_hist(const int* __restrict__ dst,
                                              int* __restrict__ hist){
    __shared__ int h[NB];
    int tid = threadIdx.x, g = blockIdx.x;
    for (int i = tid; i < NB; i += 512) h[i] = 0;
    __syncthreads();
    const int2* d2 = reinterpret_cast<const int2*>(dst + g * EPB);
    for (int i = tid; i < EPB / 2; i += 512){
        int2 d = d2[i];
        atomicAdd(&h[d.x >> BSH], 1);
        atomicAdd(&h[d.y >> BSH], 1);
    }
    __syncthreads();
    for (int i = tid; i < NB; i += 512) hist[i * G_SC + g] = h[i];  // bucket-major
}

// ---- A2: per-bucket exclusive scan over blocks -> relative cursors + bucket totals ----
__global__ __launch_bounds__(512) void k_colscan(const int* __restrict__ hist,
                                                 int* __restrict__ cursors,
                                                 int* __restrict__ btot){
    __shared__ int sm[512];
    int b = blockIdx.x, tid = threadIdx.x;
    int v = hist[b * G_SC + tid];
    sm[tid] = v; __syncthreads();
    for (int off = 1; off < 512; off <<= 1){
        int t = (tid >= off) ? sm[tid - off] : 0;
        __syncthreads(); sm[tid] += t; __syncthreads();
    }
    cursors[b * G_SC + tid] = sm[tid] - v;   // relative to bucket base
    if (tid == 511) btot[b] = sm[511];
}

// ---- A2b: exclusive scan of bucket totals -> bucket bases ----
__global__ __launch_bounds__(512) void k_bscan(const int* __restrict__ btot,
                                               int* __restrict__ bbase){
    __shared__ int sm[512];
    int tid = threadIdx.x;
    int v = (tid < NB) ? btot[tid] : 0;
    sm[tid] = v; __syncthreads();
    for (int off = 1; off < 512; off <<= 1){
        int t = (tid >= off) ? sm[tid - off] : 0;
        __syncthreads(); sm[tid] += t; __syncthreads();
    }
    if (tid < NB) bbase[tid] = sm[tid] - v;  // exclusive
    if (tid == 0) bbase[NB] = N_EDGES;
}

// ---- A3: scatter (src,dst) pairs into coarse buckets; block-private regions ----
__global__ __launch_bounds__(512) void k_scatter(const int* __restrict__ src,
                                                 const int* __restrict__ dst,
                                                 const int* __restrict__ cursors,
                                                 const int* __restrict__ bbase,
                                                 uint2* __restrict__ pairs){
    __shared__ int cur[NB];
    int g = blockIdx.x, tid = threadIdx.x;
    for (int i = tid; i < NB; i += 512) cur[i] = cursors[i * G_SC + g] + bbase[i];
    __syncthreads();
    const int2* s2 = reinterpret_cast<const int2*>(src + g * EPB);
    const int2* d2 = reinterpret_cast<const int2*>(dst + g * EPB);
    for (int i = tid; i < EPB / 2; i += 512){
        int2 s = s2[i]; int2 d = d2[i];
        int p0 = atomicAdd(&cur[d.x >> BSH], 1);
        pairs[p0] = make_uint2((u32)s.x, (u32)d.x);
        int p1 = atomicAdd(&cur[d.y >> BSH], 1);
        pairs[p1] = make_uint2((u32)s.y, (u32)d.y);
    }
}

// ---- B: fused per-bucket pass: LDS degree count -> dinv + node offsets (LDS scan)
//      -> fine CSR fill. Zero global atomics. ----
__global__ __launch_bounds__(512) void k_fine(const uint2* __restrict__ pairs,
                                              const int* __restrict__ bbase,
                                              int* __restrict__ offsets,
                                              float* __restrict__ dinv,
                                              int* __restrict__ csr_src){
    __shared__ int ldeg[256];
    __shared__ int ssc[256];
    __shared__ int lcur[256];
    int b = blockIdx.x, tid = threadIdx.x;
    int node0 = b << BSH;
    if (tid < 256) ldeg[tid] = 0;
    __syncthreads();
    int e0 = bbase[b], e1 = bbase[b + 1];
    for (int e = e0 + tid; e < e1; e += 512)
        atomicAdd(&ldeg[pairs[e].y - node0], 1);
    __syncthreads();
    int myDeg = (tid < 256) ? ldeg[tid] : 0;
    if (tid < 256) ssc[tid] = myDeg;
    __syncthreads();
    for (int off = 1; off < 256; off <<= 1){
        int t = 0;
        if (tid >= off && tid < 256) t = ssc[tid - off];
        __syncthreads();
        if (tid < 256) ssc[tid] += t;
        __syncthreads();
    }
    if (tid < 256){
        int excl = ssc[tid] - myDeg;
        int n = node0 + tid;
        if (n <= N_NODES) offsets[n] = e0 + excl;   // n==N_NODES lands on e1==N_EDGES
        if (n < N_NODES)  dinv[n] = rsqrtf((float)myDeg + 1.0f);  // +1 self loop
        lcur[tid] = e0 + excl;
    }
    __syncthreads();
    for (int e = e0 + tid; e < e1; e += 512){
        uint2 p = pairs[e];
        int pos = atomicAdd(&lcur[p.y - node0], 1);
        csr_src[pos] = (int)p.x;
    }
}

// ---- f32 -> bf16 with dinv[row] folded in; 4 floats/thread ----
__global__ void k_cvt_x(const float* __restrict__ x, const float* __restrict__ dinv,
                        u32* __restrict__ xb){
    int i = blockIdx.x * blockDim.x + threadIdx.x;  // N_NODES*32
    if (i < N_NODES * 32){
        float w = dinv[i >> 5];
        float4 f = reinterpret_cast<const float4*>(x)[i];
        uint2 p = make_uint2(pack2(f.x * w, f.y * w), pack2(f.z * w, f.w * w));
        reinterpret_cast<uint2*>(xb)[i] = p;
    }
}

// ---- both weight transposes in one launch: W[K][N] f32 -> WT[N][K] bf16 ----
__global__ void k_cvt_w(const float* __restrict__ W1, const float* __restrict__ W2,
                        u16* __restrict__ w1t, u16* __restrict__ w2t){
    int i = blockIdx.x * blockDim.x + threadIdx.x;
    if (i < 128 * 256){           // W1: K=128, N=256
        int n = i / 128, k = i % 128;
        w1t[i] = f2bf(W1[k * 256 + n]);
    } else {                      // W2: K=256, N=128
        int j = i - 128 * 256;
        int n = j / 256, k = j % 256;
        w2t[j] = f2bf(W2[k * 128 + n]);
    }
}

// ---- edge aggregation: out[v] = dinv[v] * (X'[v] + sum_{s in N(v)} X'[s])
// X' is bf16 [N][128] (pre-scaled by dinv[src]) as packed u32 pairs.
// One 64-lane group per node, 2 channels/lane. Pure gather-add, no atomics.
template<bool OUT_BF16>
__global__ __launch_bounds__(256) void k_agg(const u32* __restrict__ X,
                      const int* __restrict__ offs, const int* __restrict__ csr_src,
                      const float* __restrict__ dinv, void* __restrict__ out){
    int lane = threadIdx.x & 63;
    int v = blockIdx.x * 4 + (threadIdx.x >> 6);
    u32 u = X[v * 64 + lane];
    float a0 = bf_lo(u), a1 = bf_hi(u);
    int e1 = offs[v + 1];
    for (int e = offs[v]; e < e1; e += 64){
        int idx = e + lane;
        int sv = (idx < e1) ? csr_src[idx] : 0;
        int cnt = min(64, e1 - e);
        int j = 0;
        for (; j + 4 <= cnt; j += 4){
            int s0 = __shfl(sv, j), s1 = __shfl(sv, j+1), s2 = __shfl(sv, j+2), s3 = __shfl(sv, j+3);
            u32 u0 = X[s0*64 + lane], u1 = X[s1*64 + lane], u2 = X[s2*64 + lane], u3 = X[s3*64 + lane];
            a0 += (bf_lo(u0) + bf_lo(u1)) + (bf_lo(u2) + bf_lo(u3));
            a1 += (bf_hi(u0) + bf_hi(u1)) + (bf_hi(u2) + bf_hi(u3));
        }
        for (; j < cnt; j++){
            int s = __shfl(sv, j);
            u32 uu = X[s*64 + lane];
            a0 += bf_lo(uu); a1 += bf_hi(uu);
        }
    }
    float w = dinv[v];
    a0 *= w; a1 *= w;
    if (OUT_BF16){
        ((u32*)out)[v*64 + lane] = pack2(a0, a1);
    } else {
        ((float2*)out)[v*64 + lane] = make_float2(a0, a1);
    }
}

// ---- bf16 MFMA GEMM: C[M][BN] = A[M][BK] @ BT[BN][BK]^T (+bias)(+relu)(*rowscale)
template<int BK, int BN, bool RELU, bool BIAS, bool SCALE>
__global__ __launch_bounds__(256) void k_gemm(const u16* __restrict__ A, const u16* __restrict__ BT,
                        const float* __restrict__ bias, const float* __restrict__ rowscale,
                        u16* __restrict__ C, int M){
    extern __shared__ char smem[];
    char* As = smem;                      // 64 x BK bf16, swizzled
    char* Bs = smem + 64 * BK * 2;        // BN x BK bf16, swizzled
    const int tid = threadIdx.x;
    const int rowbytes = BK * 2;
    {
        const int a16 = 64 * rowbytes / 16;
        for (int it = tid; it < a16; it += 256){
            int flat = it * 16;
            int r = flat / rowbytes, cb = flat % rowbytes;
            int grow = blockIdx.x * 64 + r;
            int4 val = make_int4(0,0,0,0);
            if (grow < M) val = *reinterpret_cast<const int4*>(A + grow * BK + cb / 2);
            *reinterpret_cast<int4*>(As + r * rowbytes + (cb ^ ((r & 7) << 4))) = val;
        }
        const int b16 = BN * rowbytes / 16;
        for (int it = tid; it < b16; it += 256){
            int flat = it * 16;
            int r = flat / rowbytes, cb = flat % rowbytes;
            int4 val = *reinterpret_cast<const int4*>(BT + r * BK + cb / 2);
            *reinterpret_cast<int4*>(Bs + r * rowbytes + (cb ^ ((r & 7) << 4))) = val;
        }
    }
    __syncthreads();

    const int wid = tid >> 6, lane = tid & 63;
    const int r0 = wid * 16;
    constexpr int NF = BN / 16;
    f32x4 acc[NF];
#pragma unroll
    for (int i = 0; i < NF; i++) acc[i] = (f32x4){0.f,0.f,0.f,0.f};
    const int ar = r0 + (lane & 15);
    const int koff = (lane >> 4) * 8;   // element offset within k-slice
#pragma unroll
    for (int kb = 0; kb < BK / 32; kb++){
        int kbyte = (kb * 32 + koff) * 2;
        bf16x8 aF = *reinterpret_cast<const bf16x8*>(As + ar * rowbytes + (kbyte ^ ((ar & 7) << 4)));
#pragma unroll
        for (int nf = 0; nf < NF; nf++){
            int bn = nf * 16 + (lane & 15);
            bf16x8 bF = *reinterpret_cast<const bf16x8*>(Bs + bn * rowbytes + (kbyte ^ ((bn & 7) << 4)));
            acc[nf] = __builtin_amdgcn_mfma_f32_16x16x32_bf16(aF, bF, acc[nf], 0, 0, 0);
        }
    }
#pragma unroll
    for (int nf = 0; nf < NF; nf++){
        int col = nf * 16 + (lane & 15);
        float bv = BIAS ? bias[col] : 0.f;
#pragma unroll
        for (int j = 0; j < 4; j++){
            int grow = blockIdx.x * 64 + r0 + (lane >> 4) * 4 + j;
            if (grow < M){
                float val = acc[nf][j] + bv;
                if (RELU) val = fmaxf(val, 0.f);
                if (SCALE) val *= rowscale[grow];
                C[grow * BN + col] = f2bf(val);
            }
        }
    }
}

// ---- pool: batch is sorted; run-accumulate in regs, flush per graph-run ----
__global__ void k_pool(const float* __restrict__ agg2f, const int* __restrict__ batch,
                       float* __restrict__ psum, float* __restrict__ counts){
    const int NPB = 200;  // grid=500
    int n0 = blockIdx.x * NPB, n1 = min(n0 + NPB, N_NODES);
    int tid = threadIdx.x;  // 128 = channel
    float racc = 0.f; int gcur = batch[n0]; int runlen = 0;
    for (int n = n0; n < n1; n++){
        int g = batch[n];
        if (g != gcur){
            atomicAdd(&psum[gcur * 128 + tid], racc);
            if (tid == 0) atomicAdd(&counts[gcur], (float)runlen);
            racc = 0.f; runlen = 0; gcur = g;
        }
        racc += agg2f[n * 128 + tid];
        runlen++;
    }
    atomicAdd(&psum[gcur * 128 + tid], racc);
    if (tid == 0) atomicAdd(&counts[gcur], (float)runlen);
}

__global__ void k_final(const float* __restrict__ psum, const float* __restrict__ counts,
                        const float* __restrict__ b2, float* __restrict__ out){
    int g = blockIdx.x, c = threadIdx.x;
    out[g * 128 + c] = psum[g * 128 + c] / fmaxf(counts[g], 1.0f) + b2[c];
}

extern "C" void kernel_launch(void* const* d_in, const int* in_sizes, int n_in,
                              void* d_out, int out_size, void* d_ws, size_t ws_size,
                              hipStream_t stream){
    const float* x   = (const float*)d_in[0];
    const int*   ei  = (const int*)d_in[1];
    const int* batch = (const int*)d_in[2];
    const float* W1  = (const float*)d_in[3];
    const float* b1  = (const float*)d_in[4];
    const float* W2  = (const float*)d_in[5];
    const float* b2  = (const float*)d_in[6];
    float* out = (float*)d_out;
    const int* esrc = ei;
    const int* edst = ei + N_EDGES;

    char* w = (char*)d_ws;
    size_t off = 0;
    auto alloc = [&](size_t bytes) -> char* {
        char* p = w + off; off += (bytes + 255) & ~size_t(255); return p;
    };
    float* dinv     = (float*)alloc((size_t)N_NODES * 4);
    int*   offsets  = (int*)  alloc((size_t)(N_NODES + 1) * 4);
    int*   hist     = (int*)  alloc((size_t)NB * G_SC * 4);
    int*   cursors  = (int*)  alloc((size_t)NB * G_SC * 4);
    int*   btot     = (int*)  alloc((size_t)NB * 4);
    int*   bbase    = (int*)  alloc((size_t)(NB + 1) * 4);
    int*   csr_src  = (int*)  alloc((size_t)N_EDGES * 4);
    u32*   xb       = (u32*)  alloc((size_t)N_NODES * 64 * 4);   // bf16 [N][128] prescaled
    u16*   aggx     = (u16*)  alloc((size_t)N_NODES * 128 * 2);  // bf16 [N][128]
    u16*   h        = (u16*)  alloc((size_t)N_NODES * 256 * 2);  // bf16 [N][256]
    u16*   t        = (u16*)  alloc((size_t)N_NODES * 128 * 2);  // bf16 [N][128] prescaled
    u16*   w1t      = (u16*)  alloc(128 * 256 * 2);
    u16*   w2t      = (u16*)  alloc(256 * 128 * 2);
    float* psum     = (float*)alloc((size_t)N_GRAPHS * 128 * 4);
    float* counts   = (float*)alloc((size_t)N_GRAPHS * 4);
    float* agg2f    = (float*)h;   // alias: h dead once t computed; agg2 f32 [N][128]
    uint2* pairs    = (uint2*)h;   // alias: h not yet written during CSR build (25.6MB < 51.2MB)

    hipMemsetAsync(psum, 0, (size_t)N_GRAPHS * 128 * 4, stream);
    hipMemsetAsync(counts, 0, (size_t)N_GRAPHS * 4, stream);

    // counting-sort CSR build; degrees/dinv/offsets all derived bucket-locally
    k_hist   <<<G_SC, 512, 0, stream>>>(edst, hist);
    k_colscan<<<NB, 512, 0, stream>>>(hist, cursors, btot);
    k_bscan  <<<1, 512, 0, stream>>>(btot, bbase);
    k_scatter<<<G_SC, 512, 0, stream>>>(esrc, edst, cursors, bbase, pairs);
    k_fine   <<<NB, 512, 0, stream>>>(pairs, bbase, offsets, dinv, csr_src);

    k_cvt_x<<<12500, 256, 0, stream>>>(x, dinv, xb);
    k_cvt_w<<<256, 256, 0, stream>>>(W1, W2, w1t, w2t);

    // layer 1: aggx = dinv*(sum of prescaled x rows)  (bf16), h = relu(aggx@W1+b1)
    k_agg<true><<<25000, 256, 0, stream>>>(xb, offsets, csr_src, dinv, aggx);

    hipFuncSetAttribute(reinterpret_cast<const void*>(&k_gemm<128, 256, true, true, false>),
                        hipFuncAttributeMaxDynamicSharedMemorySize, 64*128*2 + 256*128*2);
    hipFuncSetAttribute(reinterpret_cast<const void*>(&k_gemm<256, 128, false, false, true>),
                        hipFuncAttributeMaxDynamicSharedMemorySize, 64*256*2 + 128*256*2);

    k_gemm<128, 256, true, true, false><<<1563, 256, 64*128*2 + 256*128*2, stream>>>(
        aggx, w1t, b1, nullptr, h, N_NODES);
    // layer 2: t = (h@W2)*dinv[row] (bf16, prescaled), agg2f = dinv*(sum of t rows) (f32)
    k_gemm<256, 128, false, false, true><<<1563, 256, 64*256*2 + 128*256*2, stream>>>(
        h, w2t, nullptr, dinv, t, N_NODES);
    k_agg<false><<<25000, 256, 0, stream>>>((const u32*)t, offsets, csr_src, dinv, (void*)agg2f);
    k_pool <<<500, 128, 0, stream>>>(agg2f, batch, psum, counts);
    k_final<<<N_GRAPHS, 128, 0, stream>>>(psum, counts, b2, out);
}